// Round 5
// baseline (138.511 us; speedup 1.0000x reference)
//
#include <hip/hip_runtime.h>
#include <float.h>

// Problem constants (from reference setup_inputs)
#define NS   16384   // samples
#define K1   512     // d_in
#define F    256     // n_feat
#define NC   1000    // n_classes
#define SPB  64      // samples per block
#define NTHR 512     // 8 waves
#define NBLK (NS / SPB)   // 256 blocks = 1 per CU

// f16 split-precision MFMA plan:
//   value = hi + lo, hi = f16(v), lo = f16(v - hi)  => 2^-22 relative capture.
//   A*B ~= Ah*Bh + Ah*Bl + Al*Bh  (ll term ~2^-22 rel, dropped).
//   Pre-scale x*8, W*16, means*16 (argmax-invariant positive scales).
// MFMA 16x16x32 f16 layouts (HW-verified m89/m91/m120):
//   A[m][k]: m=lane&15, k=(lane>>4)*8+j ; B[k][n]: n=lane&15, k=(lane>>4)*8+j
//   C/D: col=lane&15, row=(lane>>4)*4+reg
// Tie-break: reference argmin takes FIRST min => lowest class index wins.

typedef _Float16 half8  __attribute__((ext_vector_type(8)));
typedef _Float16 half4v __attribute__((ext_vector_type(4)));
typedef float    float4v __attribute__((ext_vector_type(4)));

// Workspace (halves), TILE-INTERLEAVED hi/lo:
//   W: 256 tiles (ks*16+nt) * 1024 halves (hi at +0, lo at +512)
//   M: 512 tiles (ks*64+gt) at M_OFF, same intra-tile layout
#define M_OFF 262144

#define PREP_BLKS 192
#define ZERO_BLKS 2048   // 2048 blk * 256 thr * 8 float4 = 67.1 MB >= 64 MB

// ---- merged prep: fragment swizzle + output zeroing (keeps fused store-free)
__global__ void prep(const float* __restrict__ W, const float* __restrict__ means,
                     _Float16* __restrict__ ws, float* __restrict__ out) {
    const int bid = blockIdx.x;
    if (bid >= PREP_BLKS) {
        const size_t total4 = (size_t)NS * NC / 4;
        const float4v z4 = (float4v){0.f, 0.f, 0.f, 0.f};
        size_t base = (size_t)(bid - PREP_BLKS) * 2048 + threadIdx.x;
#pragma unroll
        for (int j = 0; j < 8; ++j) {
            size_t q = base + (size_t)j * 256;
            if (q < total4)
                __builtin_nontemporal_store(z4, reinterpret_cast<float4v*>(out) + q);
        }
        return;
    }
    int g = bid * blockDim.x + threadIdx.x;            // 0..49151
    if (g < 16384) {
        int lane = g & 63, tile = g >> 6;              // tile = ks*16+nt
        int ks = tile >> 4, nt = tile & 15;
        int k0 = ks * 32 + (lane >> 4) * 8;
        int n  = nt * 16 + (lane & 15);
        half8 hv, lv;
#pragma unroll
        for (int j = 0; j < 8; ++j) {
            float v = W[(size_t)(k0 + j) * F + n] * 16.0f;
            _Float16 hi = (_Float16)v;
            hv[j] = hi;
            lv[j] = (_Float16)(v - (float)hi);
        }
        _Float16* d = ws + (size_t)tile * 1024 + (size_t)lane * 8;
        *reinterpret_cast<half8*>(d)       = hv;
        *reinterpret_cast<half8*>(d + 512) = lv;
    } else {
        int gm = g - 16384;                            // 0..32767
        int lane = gm & 63, tile = gm >> 6;            // tile = ks*64+gt
        int ks = tile >> 6, gt = tile & 63;
        int k0 = ks * 32 + (lane >> 4) * 8;
        int c  = gt * 16 + (lane & 15);
        half8 hv, lv;
#pragma unroll
        for (int j = 0; j < 8; ++j) {
            float v = (c < NC) ? means[(size_t)c * F + k0 + j] * 16.0f : 0.0f;
            _Float16 hi = (_Float16)v;
            hv[j] = hi;
            lv[j] = (_Float16)(v - (float)hi);
        }
        _Float16* d = ws + M_OFF + (size_t)tile * 1024 + (size_t)lane * 8;
        *reinterpret_cast<half8*>(d)       = hv;
        *reinterpret_cast<half8*>(d + 512) = lv;
    }
}

#define MFMA(a, b, c) __builtin_amdgcn_mfma_f32_16x16x32_f16((a), (b), (c), 0, 0, 0)

// Counted vmcnt wait (compile-time n); sched_barrier stops hoisting past it
__device__ __forceinline__ void vmwait(int n) {
    switch (n) {
        case 0: asm volatile("s_waitcnt vmcnt(0)" ::: "memory"); break;
        case 2: asm volatile("s_waitcnt vmcnt(2)" ::: "memory"); break;
        case 4: asm volatile("s_waitcnt vmcnt(4)" ::: "memory"); break;
        default: asm volatile("s_waitcnt vmcnt(6)" ::: "memory"); break;
    }
    __builtin_amdgcn_sched_barrier(0);
}

// LDS layout (halves):
//   FH [64 rows][256] at 0, FL at 16384 — stride 512B (power of 2) with
//   T2 XOR swizzle (col ^ (row&7)<<3): the 16 cl-rows of every b128 A-frag
//   read spread over all 8 bank-quads (was 8-way conflict at stride 528B).
//   OVL at 32768 (32768 halves = 64KB):
//     phase1: xsh[2][64 rows packed 2/128B line] (2048/buf) + xsl at +4096
//     phase2: per-wave means FIFO w*4096, 4 slots * 1024 halves (linear —
//             global_load_lds needs linear dest; lane*16B is conflict-free)
#define FH_OFF  0
#define FL_OFF  16384
#define OVL_OFF 32768
#define SH_HALVES 65536   // 128 KB

// swizzled accessors (all in halves)
#define FH_P(r, c) (&SH[FH_OFF + ((r) << 8) + ((c) ^ (((r) & 7) << 3))])
#define FL_P(r, c) (&SH[FL_OFF + ((r) << 8) + ((c) ^ (((r) & 7) << 3))])
#define XS_IDX(r, c) ((((r) >> 1) << 6) + ((((((r) & 1) << 5)) + (c)) ^ ((((r) >> 1) & 7) << 3)))
#define XSH_P(b, r, c) (&SH[OVL_OFF + (b) * 2048 + XS_IDX(r, c)])
#define XSL_P(b, r, c) (&SH[OVL_OFF + 4096 + (b) * 2048 + XS_IDX(r, c)])

__attribute__((amdgpu_flat_work_group_size(NTHR, NTHR), amdgpu_waves_per_eu(2, 4)))
__global__ void fused_mfma(const float* __restrict__ x,
                           const _Float16* __restrict__ ws,
                           float* __restrict__ out) {
    __shared__ _Float16 SH[SH_HALVES];
    __shared__ float cand_v[64][8];
    __shared__ int   cand_i[64][8];
    __shared__ int   bidx[64];

    const int tid  = threadIdx.x;
    const int lane = tid & 63;
    const int w    = tid >> 6;    // wave 0..7
    const int quad = lane >> 4;   // 0..3
    const int cl   = lane & 15;
    const int s0   = blockIdx.x * SPB;

    // staging coords: 512 threads cover 64 rows x 32 cols (float4 each)
    const int xrow = tid >> 3;          // 0..63
    const int xc4  = (tid & 7) * 4;     // 0,4,..,28

    // ================= Phase 1: feats = (8x) @ (16W), f16-split MFMA ========
    float4v acc1[2][4];   // [p = n-subtile][mt]
#pragma unroll
    for (int p = 0; p < 2; ++p)
#pragma unroll
        for (int mt = 0; mt < 4; ++mt)
            acc1[p][mt] = (float4v){0.f, 0.f, 0.f, 0.f};

    const _Float16* wsrc = ws + ((size_t)(w * 2) << 10) + ((size_t)lane << 3);
    half8 wbh[2][2], wbl[2][2];
#pragma unroll
    for (int p = 0; p < 2; ++p) {
        wbh[0][p] = *reinterpret_cast<const half8*>(wsrc + p * 1024);
        wbl[0][p] = *reinterpret_cast<const half8*>(wsrc + p * 1024 + 512);
    }

    float4v xv = *reinterpret_cast<const float4v*>(x + (size_t)(s0 + xrow) * K1 + xc4);

    // rolled 8x2 (buf parity static per body -> register dbuf stays static;
    // loop body ~1KB of code instead of ~6KB unrolled: I$-resident)
#define P1_BODY(k, buf) do {                                                   \
        { half4v hx, lx;                                                       \
          _Pragma("unroll") for (int j = 0; j < 4; ++j) {                      \
              float v = xv[j] * 8.0f; _Float16 hi = (_Float16)v;               \
              hx[j] = hi; lx[j] = (_Float16)(v - (float)hi); }                 \
          *reinterpret_cast<half4v*>(XSH_P(buf, xrow, xc4)) = hx;              \
          *reinterpret_cast<half4v*>(XSL_P(buf, xrow, xc4)) = lx; }            \
        __syncthreads();                                                       \
        if ((k) < 15)                                                          \
            xv = *reinterpret_cast<const float4v*>(                            \
                x + (size_t)(s0 + xrow) * K1 + ((k) + 1) * 32 + xc4);          \
        _Pragma("unroll") for (int p = 0; p < 2; ++p) {                        \
            wbh[(buf) ^ 1][p] = *reinterpret_cast<const half8*>(               \
                wsrc + (size_t)((k) + 1) * 16384 + p * 1024);                  \
            wbl[(buf) ^ 1][p] = *reinterpret_cast<const half8*>(               \
                wsrc + (size_t)((k) + 1) * 16384 + p * 1024 + 512); }          \
        half8 ah[4], al[4];                                                    \
        _Pragma("unroll") for (int mt = 0; mt < 4; ++mt) {                     \
            ah[mt] = *reinterpret_cast<const half8*>(                          \
                XSH_P(buf, mt * 16 + cl, quad * 8));                           \
            al[mt] = *reinterpret_cast<const half8*>(                          \
                XSL_P(buf, mt * 16 + cl, quad * 8)); }                         \
        __builtin_amdgcn_s_setprio(1);                                         \
        _Pragma("unroll") for (int p = 0; p < 2; ++p)                          \
            _Pragma("unroll") for (int mt = 0; mt < 4; ++mt) {                 \
                acc1[p][mt] = MFMA(ah[mt], wbh[buf][p], acc1[p][mt]);          \
                acc1[p][mt] = MFMA(ah[mt], wbl[buf][p], acc1[p][mt]);          \
                acc1[p][mt] = MFMA(al[mt], wbh[buf][p], acc1[p][mt]); }        \
        __builtin_amdgcn_s_setprio(0);                                         \
    } while (0)

    for (int k2 = 0; k2 < 8; ++k2) {
        P1_BODY(2 * k2, 0);
        P1_BODY(2 * k2 + 1, 1);
    }

    // park feats (scaled x128) into swizzled LDS as f16 hi/lo
#pragma unroll
    for (int p = 0; p < 2; ++p)
#pragma unroll
        for (int mt = 0; mt < 4; ++mt)
#pragma unroll
            for (int r = 0; r < 4; ++r) {
                int srow = mt * 16 + quad * 4 + r;
                int n    = (w * 2 + p) * 16 + cl;
                float v  = acc1[p][mt][r];
                _Float16 hi = (_Float16)v;
                *FH_P(srow, n) = hi;
                *FL_P(srow, n) = (_Float16)(v - (float)hi);
            }
    __syncthreads();   // feats visible to all; drains all phase-1 vmem

    // ========== Phase 2: scores = feats @ means.T, barrier-free pipeline ====
    // Wave w owns gt-tiles gt*8+w (classes ascending in gt). Means stream
    // through a per-wave 4-slot LDS FIFO fed by global_load_lds, 3 tiles
    // ahead, counted vmcnt(4) waits (never 0, no barriers). Rolled into a
    // 7-iteration ks loop (static slot/reg indices per unrolled gt) + peeled
    // ks=7 drain: hot loop ~1.6KB of code.
    float4v acc2[4][8];   // [mt][gt]
#pragma unroll
    for (int mt = 0; mt < 4; ++mt)
#pragma unroll
        for (int c = 0; c < 8; ++c)
            acc2[mt][c] = (float4v){0.f, 0.f, 0.f, 0.f};

    _Float16* fifo = &SH[OVL_OFF + w * 4096];
    const _Float16* mg = ws + M_OFF + ((size_t)w << 10) + ((size_t)lane << 3);

#define STAGE_OFF(goff, slot) do {                                             \
        __builtin_amdgcn_global_load_lds(                                      \
            (const __attribute__((address_space(1))) void*)(mg + (goff)),      \
            (__attribute__((address_space(3))) void*)(fifo + (slot) * 1024),   \
            16, 0, 0);                                                         \
        __builtin_amdgcn_global_load_lds(                                      \
            (const __attribute__((address_space(1))) void*)(mg + (goff) + 512),\
            (__attribute__((address_space(3))) void*)(fifo + (slot) * 1024 + 512),\
            16, 0, 0);                                                         \
    } while (0)

#define LOAD_A(kk) do { int c0_ = (kk) * 32 + quad * 8;                        \
        _Pragma("unroll") for (int mt = 0; mt < 4; ++mt) {                     \
            fah[mt] = *reinterpret_cast<const half8*>(FH_P(mt * 16 + cl, c0_));\
            fal[mt] = *reinterpret_cast<const half8*>(FL_P(mt * 16 + cl, c0_));\
        } } while (0)

#define FB_READ(slot, rb) do {                                                 \
        const _Float16* sl_ = fifo + (slot) * 1024 + lane * 8;                 \
        fbh[rb] = *reinterpret_cast<const half8*>(sl_);                        \
        fbl[rb] = *reinterpret_cast<const half8*>(sl_ + 512);                  \
    } while (0)

#define MFMA12(gt, rb) do {                                                    \
        __builtin_amdgcn_s_setprio(1);                                         \
        _Pragma("unroll") for (int mt = 0; mt < 4; ++mt) {                     \
            acc2[mt][gt] = MFMA(fah[mt], fbh[rb], acc2[mt][gt]);               \
            acc2[mt][gt] = MFMA(fah[mt], fbl[rb], acc2[mt][gt]);               \
            acc2[mt][gt] = MFMA(fal[mt], fbh[rb], acc2[mt][gt]); }             \
        __builtin_amdgcn_s_setprio(0);                                         \
    } while (0)

    half8 fah[4], fal[4];
    half8 fbh[2], fbl[2];

    // prologue: stage T0..T2 (6 loads in flight), A-frags for ks=0
    STAGE_OFF(0, 0); STAGE_OFF(8192, 1); STAGE_OFF(16384, 2);
    LOAD_A(0);
    vmwait(4);                 // T0 landed
    FB_READ(0, 0);

    for (int ks = 0; ks < 7; ++ks) {
#pragma unroll
        for (int gt = 0; gt < 8; ++gt) {
            // stage tile i+3 (crosses into next ks for gt>=5)
            if (gt < 5) STAGE_OFF((gt + 3) * 8192, (gt + 3) & 3);
            else        STAGE_OFF(65536 + (gt - 5) * 8192, (gt + 3) & 3);
            if (gt == 0 && ks > 0) LOAD_A(ks);   // ds latency hides under vmwait
            vmwait(4);                            // tile i+1 landed
            FB_READ((gt + 1) & 3, (gt + 1) & 1);  // read-ahead next tile
            MFMA12(gt, gt & 1);
        }
        mg += 65536;
    }
    // peeled ks=7 with drain schedule
#pragma unroll
    for (int gt = 0; gt < 8; ++gt) {
        if (gt < 5) STAGE_OFF((gt + 3) * 8192, (gt + 3) & 3);
        if (gt == 0) LOAD_A(7);
        if (gt < 5)       vmwait(4);
        else if (gt == 5) vmwait(2);
        else if (gt == 6) vmwait(0);
        if (gt < 7) FB_READ((gt + 1) & 3, (gt + 1) & 1);
        MFMA12(gt, gt & 1);
    }

    // ---- argmax from C/D layout: row=quad*4+r, col=cl ----
#pragma unroll
    for (int mt = 0; mt < 4; ++mt)
#pragma unroll
        for (int r = 0; r < 4; ++r) {
            float v  = -FLT_MAX;
            int   ix = 0x7FFFFFFF;
#pragma unroll
            for (int nt = 0; nt < 8; ++nt) {          // ascending class order
                int c = (nt * 8 + w) * 16 + cl;       // gtile = nt*8 + w
                if (c < NC) {
                    float sc = acc2[mt][nt][r];
                    if (sc > v) { v = sc; ix = c; }   // strict >: lowest wins
                }
            }
#pragma unroll
            for (int off = 1; off < 16; off <<= 1) {  // merge quad's 16 lanes
                float ov = __shfl_xor(v, off, 64);
                int   oi = __shfl_xor(ix, off, 64);
                if (ov > v || (ov == v && oi < ix)) { v = ov; ix = oi; }
            }
            if (cl == 0) {
                int srow = mt * 16 + quad * 4 + r;
                cand_v[srow][w] = v;
                cand_i[srow][w] = ix;
            }
        }
    __syncthreads();

    if (tid < SPB) {   // merge the 8 wave-candidates (order-independent)
        float v  = cand_v[tid][0];
        int   ix = cand_i[tid][0];
#pragma unroll
        for (int q = 1; q < 8; ++q) {
            float ov = cand_v[tid][q];
            int   oi = cand_i[tid][q];
            if (ov > v || (ov == v && oi < ix)) { v = ov; ix = oi; }
        }
        bidx[tid] = ix;
    }
    __syncthreads();

    // ===== Epilogue: single 1.0 per row (zeros written by prep's blocks) ====
    if (tid < SPB)
        out[(size_t)(s0 + tid) * NC + bidx[tid]] = 1.0f;
}

extern "C" void kernel_launch(void* const* d_in, const int* in_sizes, int n_in,
                              void* d_out, int out_size, void* d_ws, size_t ws_size,
                              hipStream_t stream) {
    const float* x     = (const float*)d_in[0];
    const float* W     = (const float*)d_in[1];
    const float* means = (const float*)d_in[2];
    float* out         = (float*)d_out;
    _Float16* ws       = (_Float16*)d_ws;   // 1.5 MB of swizzled f16 fragments

    prep<<<PREP_BLKS + ZERO_BLKS, 256, 0, stream>>>(W, means, ws, out);
    fused_mfma<<<NBLK, NTHR, 0, stream>>>(x, ws, out);
}